// Round 4
// baseline (67.605 us; speedup 1.0000x reference)
//
#include <hip/hip_runtime.h>
#include <hip/hip_fp16.h>
#include <math.h>

#define N_IMG 512
#define N_ANGLES 25
#define N_DET 512
#define DET_SPACING 3.0f
#define SRC_DIST 512.0f
#define DET_DIST 512.0f
#define N_SAMPLES 1024
#define PAD 8
#define QW 528            // padded grid side: r,c in [-8, 519]
#define NGC 132           // column groups of 4 (QW/4)

// ---------------------------------------------------------------------------
// ws: 2.23 MB zero-padded FP16 QUAD array, blocked 2(rows)x4(cols) quads per
// 64 B cache line (R3: -5 us, TA unique-line theory confirmed).
//   quad16(R,C) = half{v(r,c), v(r,c+1), v(r+1,c), v(r+1,c+1)} packed in 8 B.
//   idx = ((R>>1)*NGC + (C>>2))*8 + (R&1)*4 + (C&3)
//
// R4 change: LAUNCH GEOMETRY.  The old config (200 blocks x 256) put <1
// workgroup per CU -> 1 wave/SIMD -> zero TLP, gather latency fully exposed,
// duration set by the longest 4-ray block.  Now: ONE 64-thread block per ray
// (12800 workgroups).  Many independent 1-wave blocks pack per CU (>=4
// waves/SIMD at this VGPR count), hiding gather latency and load-balancing
// short/missing rays.  No __syncthreads / LDS -> 1-wave blocks lose nothing.
// Arithmetic unchanged -> bit-identical output (absmax stays 0.25).
// ---------------------------------------------------------------------------

__device__ __forceinline__ int qidx16(int R, int C) {
    return (((R >> 1) * NGC + (C >> 2)) << 3) + ((R & 1) << 2) + (C & 3);
}

__device__ __forceinline__ float img_at(const float* __restrict__ img, int r, int c) {
    return ((unsigned)r < N_IMG && (unsigned)c < N_IMG) ? img[(r << 9) + c] : 0.0f;
}

__global__ __launch_bounds__(256) void build_quads16(const float* __restrict__ img,
                                                     uint2* __restrict__ quad) {
    int idx = blockIdx.x * 256 + (int)threadIdx.x;
    if (idx >= QW * QW) return;
    int R = idx / QW, C = idx - R * QW;
    int r = R - PAD, c = C - PAD;
    __half2 tp = __floats2half2_rn(img_at(img, r,     c), img_at(img, r,     c + 1));
    __half2 bt = __floats2half2_rn(img_at(img, r + 1, c), img_at(img, r + 1, c + 1));
    uint2 q;
    q.x = *reinterpret_cast<unsigned int*>(&tp);
    q.y = *reinterpret_cast<unsigned int*>(&bt);
    quad[qidx16(R, C)] = q;
}

// Clip [tlo,thi] to { t : lo <= v0 + t*dv <= hi }.
__device__ __forceinline__ void slab(float v0, float dv, float lo, float hi,
                                     float& tlo, float& thi) {
    if (fabsf(dv) < 1e-8f) {
        if (v0 < lo || v0 > hi) { tlo = 1.0f; thi = 0.0f; }
    } else {
        float inv = 1.0f / dv;
        float ta = (lo - v0) * inv;
        float tb = (hi - v0) * inv;
        tlo = fmaxf(tlo, fminf(ta, tb));
        thi = fminf(thi, fmaxf(ta, tb));
    }
}

__device__ __forceinline__ float bil16(uint2 q, float fc, float fr) {
    float2 top = __half22float2(*reinterpret_cast<__half2*>(&q.x));
    float2 bot = __half22float2(*reinterpret_cast<__half2*>(&q.y));
    float tv = fmaf(fc, top.y - top.x, top.x);
    float bv = fmaf(fc, bot.y - bot.x, bot.x);
    return fmaf(fr, bv - tv, tv);
}

// One 64-thread block (= one wave) per ray; 4-deep batched loads;
// clamp-free padded inner loop.
__global__ __launch_bounds__(64) void fanbeam_kernel(const uint2* __restrict__ quad,
                                                     float* __restrict__ out) {
    const int ray  = blockIdx.x;
    const int lane = (int)threadIdx.x;

    const int a = ray >> 9;
    const int d = ray & 511;

    float beta = (2.0f * (float)a / 25.0f) * 3.14159265358979323846f;
    float c, s;
    __sincosf(beta, &s, &c);
    float t = ((float)d - (N_DET - 1) * 0.5f) * DET_SPACING;
    float srcx = -SRC_DIST * s;
    float srcy =  SRC_DIST * c;
    float dx = (t * c + DET_DIST * s) - srcx;
    float dy = (t * s - DET_DIST * c) - srcy;
    float seg = sqrtf(dx * dx + dy * dy);

    const float half = (N_IMG - 1) * 0.5f;
    const float col0 = srcx + half;            // unpadded (for clipping)
    const float row0 = half - srcy;
    const float drow = -dy;
    const float col0p = col0 + (float)PAD;     // padded-coordinate origins
    const float row0p = row0 + (float)PAD;
    const float inv_n = 1.0f / N_SAMPLES;

    float tA = 0.0f, tB = 1.0f;
    slab(col0, dx,   -1.01f, 512.01f, tA, tB);
    slab(row0, drow, -1.01f, 512.01f, tA, tB);

    float acc = 0.0f;
    if (tA <= tB) {
        int i_lo = max(0,             (int)floorf(tA * N_SAMPLES - 0.5f) - 1);
        int i_hi = min(N_SAMPLES - 1, (int)ceilf (tB * N_SAMPLES - 0.5f) + 1);
        int n = i_hi - i_lo + 1;                       // wave-uniform
        int k = 0;
        // 4-deep batches: 4 independent dwordx2 gathers in flight; padded
        // coords are always >= ~5 within the window -> trunc == floor, no clamps.
        for (; k + 256 <= n; k += 256) {
            float f0 = (float)(i_lo + k + lane);       // exact in fp32
            float acc4 = 0.0f;
            #pragma unroll
            for (int j = 0; j < 4; ++j) {
                float ts  = (f0 + (64.0f * j + 0.5f)) * inv_n;
                float col = fmaf(ts, dx,   col0p);
                float row = fmaf(ts, drow, row0p);
                float cf = floorf(col), rf = floorf(row);
                float fc = col - cf,    fr = row - rf;
                uint2 q = quad[qidx16((int)rf, (int)cf)];
                acc4 += bil16(q, fc, fr);
            }
            acc += acc4;
        }
        // Tail (< 4 strides): plain loop, still clamp-free.
        #pragma unroll 2
        for (int i = i_lo + k + lane; i <= i_hi; i += 64) {
            float ts  = ((float)i + 0.5f) * inv_n;
            float col = fmaf(ts, dx,   col0p);
            float row = fmaf(ts, drow, row0p);
            float cf = floorf(col), rf = floorf(row);
            float fc = col - cf,    fr = row - rf;
            uint2 q = quad[qidx16((int)rf, (int)cf)];
            acc += bil16(q, fc, fr);
        }
    }

    #pragma unroll
    for (int off = 32; off > 0; off >>= 1)
        acc += __shfl_down(acc, off, 64);

    if (lane == 0) out[ray] = acc * (seg * inv_n);
}

extern "C" void kernel_launch(void* const* d_in, const int* in_sizes, int n_in,
                              void* d_out, int out_size, void* d_ws, size_t ws_size,
                              hipStream_t stream) {
    const float* img = (const float*)d_in[0];
    float* out = (float*)d_out;
    uint2* quad = (uint2*)d_ws;                    // 528*528*8 B = 2.23 MB

    build_quads16<<<(QW * QW + 255) / 256, 256, 0, stream>>>(img, quad);

    const int n_rays = N_ANGLES * N_DET;           // 12800 rays, 1 wave each
    fanbeam_kernel<<<n_rays, 64, 0, stream>>>(quad, out);
}